// Round 5
// baseline (164.214 us; speedup 1.0000x reference)
//
#include <hip/hip_runtime.h>
#include <hip/hip_bf16.h>

typedef __attribute__((ext_vector_type(8))) short short8;
typedef __attribute__((ext_vector_type(4))) short short4_t;
typedef __attribute__((ext_vector_type(4))) float float4_;

#define LOG2E 1.4426950408889634f

__device__ __forceinline__ short f2bf(float f) {
    unsigned int u = __builtin_bit_cast(unsigned int, f);
    u = (u + 0x7FFFu + ((u >> 16) & 1u)) >> 16;
    return (short)u;
}

// pack two floats to bf16x2 (round-half-up): low short = a, high = b
__device__ __forceinline__ unsigned pk2bf(float a, float b) {
    unsigned ua = __builtin_bit_cast(unsigned, a) + 0x8000u;
    unsigned ub = __builtin_bit_cast(unsigned, b) + 0x8000u;
    return __builtin_amdgcn_perm(ub, ua, 0x07060302);
}

// butterfly swap of lane-bit5 <-> register-select bit (builtin: {new_vdst,new_src0})
__device__ __forceinline__ void pl32swap(unsigned &a, unsigned &b) {
    auto r = __builtin_amdgcn_permlane32_swap(a, b, false, false);
    a = r[0]; b = r[1];
}
// butterfly swap of lane-bit4 <-> register-select bit
__device__ __forceinline__ void pl16swap(unsigned &a, unsigned &b) {
    auto r = __builtin_amdgcn_permlane16_swap(a, b, false, false);
    a = r[0]; b = r[1];
}

union U4 { unsigned u[4]; short8 s; };

__device__ __forceinline__ void gload_lds16(const short* g, short* l) {
    __builtin_amdgcn_global_load_lds((const __attribute__((address_space(1))) void*)g,
                                     (__attribute__((address_space(3))) void*)l, 16, 0, 0);
}

// ---------------- convert fp32 -> bf16 (fold SCALE*LOG2E into Wq; stack Wq|Wk|Wv) ----------------
__global__ __launch_bounds__(256) void cvt_kernel(
    const float* __restrict__ X, const float* __restrict__ Wq, const float* __restrict__ Wk,
    const float* __restrict__ Wv, const float* __restrict__ Wo,
    short* __restrict__ Xb, short* __restrict__ Wqkvb, short* __restrict__ Wob) {
    int i = blockIdx.x * 256 + threadIdx.x;
    const float* src; short* dst; float sc = 1.0f;
    if (i < 1048576) { src = X + (size_t)i * 4; dst = Xb + (size_t)i * 4; }
    else {
        int w = i - 1048576; int sec = w >> 16; int j = (w & 65535) * 4;
        if (sec == 0)      { src = Wq + j; dst = Wqkvb + j; sc = 0.125f * LOG2E; }
        else if (sec == 1) { src = Wk + j; dst = Wqkvb + 262144 + j; }
        else if (sec == 2) { src = Wv + j; dst = Wqkvb + 524288 + j; }
        else               { src = Wo + j; dst = Wob + j; }
    }
    float4 v = *(const float4*)src;
    short4_t o;
    o[0] = f2bf(v.x * sc); o[1] = f2bf(v.y * sc); o[2] = f2bf(v.z * sc); o[3] = f2bf(v.w * sc);
    *(short4_t*)dst = o;
}

// ---------------- fused QKV projection GEMM, BK=64, VGPR-pipelined staging ----------------
__global__ __launch_bounds__(256) void gemm_qkv(const short* __restrict__ A, const short* __restrict__ B,
                                                const int* __restrict__ mask,
                                                short* __restrict__ Qb, short* __restrict__ Kb,
                                                short* __restrict__ Vtb) {
    __shared__ __align__(16) short smemAB[2 * 8192];   // At | Bt, 16 KB each
    __shared__ int maskL[128];
    short* At = smemAB;
    short* Bt = smemAB + 8192;
    constexpr int K = 512;
    int tid = threadIdx.x;
    int wid = tid >> 6, lane = tid & 63;
    int quad = lane >> 4, cc = lane & 15;
    int c7 = cc & 7;
    int wr = wid >> 1, wc = wid & 1;
    int m0 = blockIdx.y * 128, n0 = blockIdx.x * 128;
    if (tid < 128) maskL[tid] = mask[m0 + tid];

    // staging: 4 chunks (16B) each for A and B per thread, XOR-swizzled k-offsets
    const short* gA[4]; const short* gB[4]; int lofs[4];
#pragma unroll
    for (int p = 0; p < 4; ++p) {
        int slot = p * 256 + tid;          // 0..1023
        int r = slot >> 3, c = slot & 7;
        int cs = (c ^ (r & 7)) * 8;
        gA[p] = A + (size_t)(m0 + r) * K + cs;
        gB[p] = B + (size_t)(n0 + r) * K + cs;
        lofs[p] = slot * 8;
    }
    short8 arg[4], brg[4];
#pragma unroll
    for (int p = 0; p < 4; ++p) { arg[p] = *(const short8*)gA[p]; brg[p] = *(const short8*)gB[p]; }

    float4_ acc[4][4] = {};

    for (int kk = 0; kk < K; kk += 64) {
        __syncthreads();                    // prev iter's LDS reads done
#pragma unroll
        for (int p = 0; p < 4; ++p) {
            *(short8*)(At + lofs[p]) = arg[p];
            *(short8*)(Bt + lofs[p]) = brg[p];
        }
        if (kk < K - 64) {                  // start loads for next tile (waited at next iter's ds_write)
#pragma unroll
            for (int p = 0; p < 4; ++p) {
                arg[p] = *(const short8*)(gA[p] + kk + 64);
                brg[p] = *(const short8*)(gB[p] + kk + 64);
            }
        }
        __syncthreads();                    // tile visible
#pragma unroll
        for (int kc = 0; kc < 2; ++kc) {
            short8 af[4], bf[4];
#pragma unroll
            for (int i = 0; i < 4; ++i)
                af[i] = *(const short8*)(At + (wr * 64 + i * 16 + cc) * 64 + (((kc * 4 + quad) ^ c7) * 8));
#pragma unroll
            for (int j = 0; j < 4; ++j)
                bf[j] = *(const short8*)(Bt + (wc * 64 + j * 16 + cc) * 64 + (((kc * 4 + quad) ^ c7) * 8));
#pragma unroll
            for (int i = 0; i < 4; ++i)
#pragma unroll
                for (int j = 0; j < 4; ++j)
                    acc[i][j] = __builtin_amdgcn_mfma_f32_16x16x32_bf16(af[i], bf[j], acc[i][j], 0, 0, 0);
        }
    }

    int which = n0 >> 9;           // block-uniform: 0=Q, 1=K, 2=V
    int b = m0 >> 11;              // block-uniform batch
    if (which == 2) {
        // ---- V^T via LDS transpose: T[d_l][nn_l], 16B-granule XOR swizzle ----
        __syncthreads();           // K-loop LDS reads done; reuse smemAB as T (32 KB)
        short* T = smemAB;
#pragma unroll
        for (int i = 0; i < 4; ++i) {
#pragma unroll
            for (int j = 0; j < 4; ++j) {
                int d_l = wc * 64 + j * 16 + cc;
                int nnb = wr * 64 + i * 16 + quad * 4;        // 4-aligned
                int G = nnb >> 3, half = (nnb >> 2) & 1;
                int Gs = G ^ (d_l & 15);
                short4_t pv;
                pv[0] = f2bf(acc[i][j][0]); pv[1] = f2bf(acc[i][j][1]);
                pv[2] = f2bf(acc[i][j][2]); pv[3] = f2bf(acc[i][j][3]);
                *(short4_t*)(T + d_l * 128 + Gs * 8 + half * 4) = pv;
            }
        }
        __syncthreads();
        // coalesced store: 2048 granules (16B), lane-consecutive along nn
#pragma unroll
        for (int p = 0; p < 8; ++p) {
            int slot = p * 256 + tid;           // 0..2047
            int d = slot >> 4, G = slot & 15;
            short8 v = *(const short8*)(T + d * 128 + ((G ^ (d & 15)) * 8));
            *(short8*)(Vtb + ((size_t)(b * 512 + (n0 & 511) + d)) * 2048 + (m0 & 2047) + G * 8) = v;
        }
    } else {
        short* dst = which ? Kb : Qb;
#pragma unroll
        for (int i = 0; i < 4; ++i) {
#pragma unroll
            for (int j = 0; j < 4; ++j) {
#pragma unroll
                for (int r = 0; r < 4; ++r) {
                    int lm = wr * 64 + i * 16 + quad * 4 + r;
                    int nn = (m0 & 2047) + lm;
                    int hd = (n0 & 511) + wc * 64 + j * 16 + cc;
                    int h = hd >> 6, dh = hd & 63;
                    float v = acc[i][j][r];
                    if (which == 1 && maskL[lm] == 0) v = 0.0f;   // zero masked K rows
                    dst[((((size_t)b * 8 + h) * 2048 + nn) * 64) + dh] = f2bf(v);
                }
            }
        }
    }
}

// ---------------- flash attention v8 (round-3 validated version, verbatim) ----------------
// grid (32 bh, 32 ty): 1024 blocks, 4 blocks/CU, 16 waves/CU. Each wave owns 16 t-rows.
// K and V double-buffered in LDS (32 KB), fragments wave-invariant -> broadcast reads.
// P stays wave-local: QK computed as mfma(K,Q), transposed in-register via permlane swaps.
__global__ __launch_bounds__(256, 4) void attn_kernel(const short* __restrict__ Q, const short* __restrict__ Kg,
                                                      const short* __restrict__ Vt,
                                                      short* __restrict__ AO) {
    __shared__ __align__(16) short KbufL[2 * 4096];    // 16 KB dbuf K tile [64 s][64 d] swizzled
    __shared__ __align__(16) short VbufL[2 * 4096];    // 16 KB dbuf V^T tile [64 d][64 s] swizzled

    int tid = threadIdx.x;
    int w = tid >> 6, lane = tid & 63;
    int quad = lane >> 4, cc = lane & 15;
    int c7 = cc & 7;
    int bh = blockIdx.x, b = bh >> 3, h = bh & 7;
    int t0 = blockIdx.y * 64 + w * 16;                 // wave-owned t chunk (16 rows)
    size_t kbase = (size_t)bh * 2048 * 64;
    size_t vbase = (size_t)b * 512 * 2048 + (size_t)h * 64 * 2048;

    // Q fragments (B-operand: col=cc -> t, k = kc*32+quad*8+j)
    short8 qf[2];
#pragma unroll
    for (int kc = 0; kc < 2; ++kc)
        qf[kc] = *(const short8*)(Q + kbase + (size_t)(t0 + cc) * 64 + kc * 32 + quad * 8);

    // shared offset table: row = rb*16+cc (s for K, d for V), swizzled 16B granule
    int koff[4][2];
#pragma unroll
    for (int rb = 0; rb < 4; ++rb)
#pragma unroll
        for (int kc = 0; kc < 2; ++kc)
            koff[rb][kc] = (rb * 16 + cc) * 64 + (((kc * 4 + quad) ^ c7) * 8);

    // staging: 2 x 16B per thread per buffer, pre-swizzled global source, linear LDS dest
    int sA = tid >> 3, cA = tid & 7;
    const short* gK0 = Kg + kbase + (size_t)sA * 64 + ((cA ^ (sA & 7)) * 8);
    const short* gK1 = gK0 + 32 * 64;
    const short* gV0 = Vt + vbase + (size_t)sA * 2048 + ((cA ^ (sA & 7)) * 8);
    const short* gV1 = gV0 + 32 * 2048;
    int ld0 = tid * 8, ld1 = tid * 8 + 2048;

    short8 krg0 = *(const short8*)gK0, krg1 = *(const short8*)gK1;
    short8 vrg0 = *(const short8*)gV0, vrg1 = *(const short8*)gV1;
    gK0 += 4096; gK1 += 4096; gV0 += 64; gV1 += 64;
    *(short8*)(KbufL + ld0) = krg0; *(short8*)(KbufL + ld1) = krg1;
    *(short8*)(VbufL + ld0) = vrg0; *(short8*)(VbufL + ld1) = vrg1;
    krg0 = *(const short8*)gK0; krg1 = *(const short8*)gK1;
    vrg0 = *(const short8*)gV0; vrg1 = *(const short8*)gV1;
    gK0 += 4096; gK1 += 4096; gV0 += 64; gV1 += 64;

    float4_ o[4] = {};            // o[db]: O[t16][d = db*16+cc]
    float lp = 0.f;               // partial row-sum for t=cc over this lane's s-slots

#pragma unroll 2
    for (int it = 0; it < 32; ++it) {
        __syncthreads();                        // dbuf handoff (only barrier per iter)
        int cur = it & 1;
        const short* Kt  = KbufL + cur * 4096;
        const short* Vtt = VbufL + cur * 4096;
        if (it < 31) {
            short* Kn = KbufL + (cur ^ 1) * 4096;
            short* Vn = VbufL + (cur ^ 1) * 4096;
            *(short8*)(Kn + ld0) = krg0; *(short8*)(Kn + ld1) = krg1;
            *(short8*)(Vn + ld0) = vrg0; *(short8*)(Vn + ld1) = vrg1;
        }
        if (it < 30) {
            krg0 = *(const short8*)gK0; krg1 = *(const short8*)gK1;
            vrg0 = *(const short8*)gV0; vrg1 = *(const short8*)gV1;
            gK0 += 4096; gK1 += 4096; gV0 += 64; gV1 += 64;
        }

        // ---- QK^T: acc[sb] = D[s16][t16], lane: col=cc->t, row=quad*4+r->s ----
        float4_ acc[4];
        __builtin_amdgcn_s_setprio(1);
#pragma unroll
        for (int sb = 0; sb < 4; ++sb) {
            short8 kf0 = *(const short8*)(Kt + koff[sb][0]);
            short8 kf1 = *(const short8*)(Kt + koff[sb][1]);
            float4_ z = {0.f, 0.f, 0.f, 0.f};
            z = __builtin_amdgcn_mfma_f32_16x16x32_bf16(kf0, qf[0], z, 0, 0, 0);
            acc[sb] = __builtin_amdgcn_mfma_f32_16x16x32_bf16(kf1, qf[1], z, 0, 0, 0);
        }
        __builtin_amdgcn_s_setprio(0);

        // ---- exp2 + wave-local row-sum + pack to bf16x2 words ----
        unsigned Wp[4][2];                      // [sb][word]: word w = P[s=sb*16+quad*4+2w+{0,1}][t=cc]
#pragma unroll
        for (int sb = 0; sb < 4; ++sb) {
            float x0 = __builtin_amdgcn_exp2f(acc[sb][0]);
            float x1 = __builtin_amdgcn_exp2f(acc[sb][1]);
            float x2 = __builtin_amdgcn_exp2f(acc[sb][2]);
            float x3 = __builtin_amdgcn_exp2f(acc[sb][3]);
            lp += (x0 + x1) + (x2 + x3);
            Wp[sb][0] = pk2bf(x0, x1);
            Wp[sb][1] = pk2bf(x2, x3);
        }

        // ---- in-register transpose P -> PV A-fragments (validated permlane butterfly) ----
        short8 pa[2];
#pragma unroll
        for (int kc = 0; kc < 2; ++kc) {
            unsigned a0 = Wp[2 * kc][0], a1 = Wp[2 * kc][1];
            unsigned b0 = Wp[2 * kc + 1][0], b1 = Wp[2 * kc + 1][1];
            pl32swap(a0, b0); pl32swap(a1, b1);
            pl16swap(a0, b0); pl16swap(a1, b1);
            U4 u; u.u[0] = a0; u.u[1] = a1; u.u[2] = b0; u.u[3] = b1;
            pa[kc] = u.s;
        }

        // ---- PV: o[db] += P^T[t16][s32] x V[s32][d16] (V frags broadcast from LDS) ----
        __builtin_amdgcn_s_setprio(1);
#pragma unroll
        for (int db = 0; db < 4; ++db) {
            short8 vf0 = *(const short8*)(Vtt + koff[db][0]);
            short8 vf1 = *(const short8*)(Vtt + koff[db][1]);
            o[db] = __builtin_amdgcn_mfma_f32_16x16x32_bf16(pa[0], vf0, o[db], 0, 0, 0);
            o[db] = __builtin_amdgcn_mfma_f32_16x16x32_bf16(pa[1], vf1, o[db], 0, 0, 0);
        }
        __builtin_amdgcn_s_setprio(0);
    }

    // ---- epilogue: wave-local softmax denominators, scale, store ----
    float s = lp;
    s += __shfl_xor(s, 16, 64);
    s += __shfl_xor(s, 32, 64);                 // lane holds full denom for t = cc
    float inv = 1.0f / s;
#pragma unroll
    for (int r = 0; r < 4; ++r) {
        int tl = quad * 4 + r;
        float iv = __shfl(inv, tl, 64);         // pull denom for this o-row (lane tl has cc=tl)
        size_t rowbase = ((size_t)(b * 2048 + t0 + tl)) * 512 + h * 64;
#pragma unroll
        for (int db = 0; db < 4; ++db)
            AO[rowbase + db * 16 + cc] = f2bf(o[db][r] * iv);
    }
}

// ---------------- output GEMM v2: 128x64 tiles, BK=64, VGPR-pipelined (qkv-clone), C fp32 ----------------
// grid (8, 64) = 512 blocks (2/CU). Wave (wr,wc): rows wr*64+[0,64), cols wc*32+[0,32).
__global__ __launch_bounds__(256) void gemm_out(const short* __restrict__ A, const short* __restrict__ B,
                                                float* __restrict__ C) {
    __shared__ __align__(16) short smemAB[8192 + 4096];   // At 16 KB | Bt 8 KB
    short* At = smemAB;
    short* Bt = smemAB + 8192;
    constexpr int K = 512;
    int tid = threadIdx.x;
    int wid = tid >> 6, lane = tid & 63;
    int quad = lane >> 4, cc = lane & 15;
    int c7 = cc & 7;
    int wr = wid >> 1, wc = wid & 1;
    int m0 = blockIdx.y * 128, n0 = blockIdx.x * 64;

    // staging: A 4 chunks, B 2 chunks (16B each) per thread, XOR-swizzled k-offsets
    const short* gA[4]; const short* gB[2]; int lofsA[4], lofsB[2];
#pragma unroll
    for (int p = 0; p < 4; ++p) {
        int slot = p * 256 + tid;          // 0..1023 -> A rows 0..127
        int r = slot >> 3, c = slot & 7;
        int cs = (c ^ (r & 7)) * 8;
        gA[p] = A + (size_t)(m0 + r) * K + cs;
        lofsA[p] = slot * 8;
    }
#pragma unroll
    for (int p = 0; p < 2; ++p) {
        int slot = p * 256 + tid;          // 0..511 -> B rows 0..63
        int r = slot >> 3, c = slot & 7;
        int cs = (c ^ (r & 7)) * 8;
        gB[p] = B + (size_t)(n0 + r) * K + cs;
        lofsB[p] = slot * 8;
    }
    short8 arg[4], brg[2];
#pragma unroll
    for (int p = 0; p < 4; ++p) arg[p] = *(const short8*)gA[p];
#pragma unroll
    for (int p = 0; p < 2; ++p) brg[p] = *(const short8*)gB[p];

    float4_ acc[4][2] = {};

    for (int kk = 0; kk < K; kk += 64) {
        __syncthreads();                    // prev iter's LDS reads done
#pragma unroll
        for (int p = 0; p < 4; ++p) *(short8*)(At + lofsA[p]) = arg[p];
#pragma unroll
        for (int p = 0; p < 2; ++p) *(short8*)(Bt + lofsB[p]) = brg[p];
        if (kk < K - 64) {
#pragma unroll
            for (int p = 0; p < 4; ++p) arg[p] = *(const short8*)(gA[p] + kk + 64);
#pragma unroll
            for (int p = 0; p < 2; ++p) brg[p] = *(const short8*)(gB[p] + kk + 64);
        }
        __syncthreads();                    // tile visible
#pragma unroll
        for (int kc = 0; kc < 2; ++kc) {
            short8 af[4], bf[2];
#pragma unroll
            for (int i = 0; i < 4; ++i)
                af[i] = *(const short8*)(At + (wr * 64 + i * 16 + cc) * 64 + (((kc * 4 + quad) ^ c7) * 8));
#pragma unroll
            for (int j = 0; j < 2; ++j)
                bf[j] = *(const short8*)(Bt + (wc * 32 + j * 16 + cc) * 64 + (((kc * 4 + quad) ^ c7) * 8));
#pragma unroll
            for (int i = 0; i < 4; ++i)
#pragma unroll
                for (int j = 0; j < 2; ++j)
                    acc[i][j] = __builtin_amdgcn_mfma_f32_16x16x32_bf16(af[i], bf[j], acc[i][j], 0, 0, 0);
        }
    }

#pragma unroll
    for (int i = 0; i < 4; ++i)
#pragma unroll
        for (int j = 0; j < 2; ++j)
#pragma unroll
            for (int r = 0; r < 4; ++r) {
                int gm = m0 + wr * 64 + i * 16 + quad * 4 + r;
                int gn = n0 + wc * 32 + j * 16 + cc;
                C[(size_t)gm * 512 + gn] = acc[i][j][r];
            }
}

extern "C" void kernel_launch(void* const* d_in, const int* in_sizes, int n_in,
                              void* d_out, int out_size, void* d_ws, size_t ws_size,
                              hipStream_t stream) {
    const float* X  = (const float*)d_in[0];
    const int* mask = (const int*)d_in[1];
    const float* Wq = (const float*)d_in[2];
    const float* Wk = (const float*)d_in[3];
    const float* Wv = (const float*)d_in[4];
    const float* Wo = (const float*)d_in[5];

    char* ws = (char*)d_ws;
    short* Xbf   = (short*)(ws + 0);              // 8192*512*2       = 8,388,608
    short* Wqkvb = (short*)(ws + 8388608);        // 1536*512*2       = 1,572,864
    short* Wob   = (short*)(ws + 9961472);        // 512*512*2        =   524,288
    short* Qb    = (short*)(ws + 10485760);       // [b,h,n,dh] bf16  = 8,388,608
    short* Kb    = (short*)(ws + 18874368);       // [b,h,n,dh] bf16  = 8,388,608
    short* Vtb   = (short*)(ws + 27262976);       // [b,dv,n]  bf16   = 8,388,608
    short* AOb   = (short*)(ws + 35651584);       // [b,n,512] bf16   = 8,388,608

    cvt_kernel<<<5120, 256, 0, stream>>>(X, Wq, Wk, Wv, Wo, Xbf, Wqkvb, Wob);
    gemm_qkv<<<dim3(12, 64), 256, 0, stream>>>(Xbf, Wqkvb, mask, Qb, Kb, Vtb);
    attn_kernel<<<dim3(32, 32), 256, 0, stream>>>(Qb, Kb, Vtb, AOb);
    gemm_out<<<dim3(8, 64), 256, 0, stream>>>(AOb, Wob, (float*)d_out);
}

// Round 6
// 162.865 us; speedup vs baseline: 1.0083x; 1.0083x over previous
//
#include <hip/hip_runtime.h>
#include <hip/hip_bf16.h>

typedef __attribute__((ext_vector_type(8))) short short8;
typedef __attribute__((ext_vector_type(4))) short short4_t;
typedef __attribute__((ext_vector_type(4))) float float4_;

#define LOG2E 1.4426950408889634f

__device__ __forceinline__ short f2bf(float f) {
    unsigned int u = __builtin_bit_cast(unsigned int, f);
    u = (u + 0x7FFFu + ((u >> 16) & 1u)) >> 16;
    return (short)u;
}

// pack two floats to bf16x2 (round-half-up): low short = a, high = b
__device__ __forceinline__ unsigned pk2bf(float a, float b) {
    unsigned ua = __builtin_bit_cast(unsigned, a) + 0x8000u;
    unsigned ub = __builtin_bit_cast(unsigned, b) + 0x8000u;
    return __builtin_amdgcn_perm(ub, ua, 0x07060302);
}

// butterfly swap of lane-bit5 <-> register-select bit (builtin: {new_vdst,new_src0})
__device__ __forceinline__ void pl32swap(unsigned &a, unsigned &b) {
    auto r = __builtin_amdgcn_permlane32_swap(a, b, false, false);
    a = r[0]; b = r[1];
}
// butterfly swap of lane-bit4 <-> register-select bit
__device__ __forceinline__ void pl16swap(unsigned &a, unsigned &b) {
    auto r = __builtin_amdgcn_permlane16_swap(a, b, false, false);
    a = r[0]; b = r[1];
}

union U4 { unsigned u[4]; short8 s; };

__device__ __forceinline__ void gload_lds16(const short* g, short* l) {
    __builtin_amdgcn_global_load_lds((const __attribute__((address_space(1))) void*)g,
                                     (__attribute__((address_space(3))) void*)l, 16, 0, 0);
}

// ---------------- convert fp32 -> bf16 (fold SCALE*LOG2E into Wq; stack Wq|Wk|Wv) ----------------
__global__ __launch_bounds__(256) void cvt_kernel(
    const float* __restrict__ X, const float* __restrict__ Wq, const float* __restrict__ Wk,
    const float* __restrict__ Wv, const float* __restrict__ Wo,
    short* __restrict__ Xb, short* __restrict__ Wqkvb, short* __restrict__ Wob) {
    int i = blockIdx.x * 256 + threadIdx.x;
    const float* src; short* dst; float sc = 1.0f;
    if (i < 1048576) { src = X + (size_t)i * 4; dst = Xb + (size_t)i * 4; }
    else {
        int w = i - 1048576; int sec = w >> 16; int j = (w & 65535) * 4;
        if (sec == 0)      { src = Wq + j; dst = Wqkvb + j; sc = 0.125f * LOG2E; }
        else if (sec == 1) { src = Wk + j; dst = Wqkvb + 262144 + j; }
        else if (sec == 2) { src = Wv + j; dst = Wqkvb + 524288 + j; }
        else               { src = Wo + j; dst = Wob + j; }
    }
    float4 v = *(const float4*)src;
    short4_t o;
    o[0] = f2bf(v.x * sc); o[1] = f2bf(v.y * sc); o[2] = f2bf(v.z * sc); o[3] = f2bf(v.w * sc);
    *(short4_t*)dst = o;
}

// ---------------- fused QKV projection GEMM, BK=64, VGPR-pipelined staging ----------------
__global__ __launch_bounds__(256) void gemm_qkv(const short* __restrict__ A, const short* __restrict__ B,
                                                const int* __restrict__ mask,
                                                short* __restrict__ Qb, short* __restrict__ Kb,
                                                short* __restrict__ Vtb) {
    __shared__ __align__(16) short smemAB[2 * 8192];   // At | Bt, 16 KB each
    __shared__ int maskL[128];
    short* At = smemAB;
    short* Bt = smemAB + 8192;
    constexpr int K = 512;
    int tid = threadIdx.x;
    int wid = tid >> 6, lane = tid & 63;
    int quad = lane >> 4, cc = lane & 15;
    int c7 = cc & 7;
    int wr = wid >> 1, wc = wid & 1;
    int m0 = blockIdx.y * 128, n0 = blockIdx.x * 128;
    if (tid < 128) maskL[tid] = mask[m0 + tid];

    // staging: 4 chunks (16B) each for A and B per thread, XOR-swizzled k-offsets
    const short* gA[4]; const short* gB[4]; int lofs[4];
#pragma unroll
    for (int p = 0; p < 4; ++p) {
        int slot = p * 256 + tid;          // 0..1023
        int r = slot >> 3, c = slot & 7;
        int cs = (c ^ (r & 7)) * 8;
        gA[p] = A + (size_t)(m0 + r) * K + cs;
        gB[p] = B + (size_t)(n0 + r) * K + cs;
        lofs[p] = slot * 8;
    }
    short8 arg[4], brg[4];
#pragma unroll
    for (int p = 0; p < 4; ++p) { arg[p] = *(const short8*)gA[p]; brg[p] = *(const short8*)gB[p]; }

    float4_ acc[4][4] = {};

    for (int kk = 0; kk < K; kk += 64) {
        __syncthreads();                    // prev iter's LDS reads done
#pragma unroll
        for (int p = 0; p < 4; ++p) {
            *(short8*)(At + lofs[p]) = arg[p];
            *(short8*)(Bt + lofs[p]) = brg[p];
        }
        if (kk < K - 64) {                  // start loads for next tile (waited at next iter's ds_write)
#pragma unroll
            for (int p = 0; p < 4; ++p) {
                arg[p] = *(const short8*)(gA[p] + kk + 64);
                brg[p] = *(const short8*)(gB[p] + kk + 64);
            }
        }
        __syncthreads();                    // tile visible
#pragma unroll
        for (int kc = 0; kc < 2; ++kc) {
            short8 af[4], bf[4];
#pragma unroll
            for (int i = 0; i < 4; ++i)
                af[i] = *(const short8*)(At + (wr * 64 + i * 16 + cc) * 64 + (((kc * 4 + quad) ^ c7) * 8));
#pragma unroll
            for (int j = 0; j < 4; ++j)
                bf[j] = *(const short8*)(Bt + (wc * 64 + j * 16 + cc) * 64 + (((kc * 4 + quad) ^ c7) * 8));
#pragma unroll
            for (int i = 0; i < 4; ++i)
#pragma unroll
                for (int j = 0; j < 4; ++j)
                    acc[i][j] = __builtin_amdgcn_mfma_f32_16x16x32_bf16(af[i], bf[j], acc[i][j], 0, 0, 0);
        }
    }

    int which = n0 >> 9;           // block-uniform: 0=Q, 1=K, 2=V
    int b = m0 >> 11;              // block-uniform batch
    if (which == 2) {
        // ---- V^T via LDS transpose: T[d_l][nn_l], 16B-granule XOR swizzle ----
        __syncthreads();           // K-loop LDS reads done; reuse smemAB as T (32 KB)
        short* T = smemAB;
#pragma unroll
        for (int i = 0; i < 4; ++i) {
#pragma unroll
            for (int j = 0; j < 4; ++j) {
                int d_l = wc * 64 + j * 16 + cc;
                int nnb = wr * 64 + i * 16 + quad * 4;        // 4-aligned
                int G = nnb >> 3, half = (nnb >> 2) & 1;
                int Gs = G ^ (d_l & 15);
                short4_t pv;
                pv[0] = f2bf(acc[i][j][0]); pv[1] = f2bf(acc[i][j][1]);
                pv[2] = f2bf(acc[i][j][2]); pv[3] = f2bf(acc[i][j][3]);
                *(short4_t*)(T + d_l * 128 + Gs * 8 + half * 4) = pv;
            }
        }
        __syncthreads();
        // coalesced store: 2048 granules (16B), lane-consecutive along nn
#pragma unroll
        for (int p = 0; p < 8; ++p) {
            int slot = p * 256 + tid;           // 0..2047
            int d = slot >> 4, G = slot & 15;
            short8 v = *(const short8*)(T + d * 128 + ((G ^ (d & 15)) * 8));
            *(short8*)(Vtb + ((size_t)(b * 512 + (n0 & 511) + d)) * 2048 + (m0 & 2047) + G * 8) = v;
        }
    } else {
        short* dst = which ? Kb : Qb;
#pragma unroll
        for (int i = 0; i < 4; ++i) {
#pragma unroll
            for (int j = 0; j < 4; ++j) {
#pragma unroll
                for (int r = 0; r < 4; ++r) {
                    int lm = wr * 64 + i * 16 + quad * 4 + r;
                    int nn = (m0 & 2047) + lm;
                    int hd = (n0 & 511) + wc * 64 + j * 16 + cc;
                    int h = hd >> 6, dh = hd & 63;
                    float v = acc[i][j][r];
                    if (which == 1 && maskL[lm] == 0) v = 0.0f;   // zero masked K rows
                    dst[((((size_t)b * 8 + h) * 2048 + nn) * 64) + dh] = f2bf(v);
                }
            }
        }
    }
}

// ---------------- flash attention v10: v8 partition + DMA (global_load_lds) staging ----------------
// grid (32 bh, 32 ty): 1024 blocks, 4 blocks/CU, 16 waves/CU. Each wave owns 16 t-rows.
// K and V double-buffered in LDS (32 KB); staging via global_load_lds DMA (no reg round-trip,
// no ds_write instrs). P stays wave-local via permlane transpose. One barrier per s-tile.
__global__ __launch_bounds__(256, 4) void attn_kernel(const short* __restrict__ Q, const short* __restrict__ Kg,
                                                      const short* __restrict__ Vt,
                                                      short* __restrict__ AO) {
    __shared__ __align__(16) short KbufL[2 * 4096];    // 16 KB dbuf K tile [64 s][64 d] swizzled
    __shared__ __align__(16) short VbufL[2 * 4096];    // 16 KB dbuf V^T tile [64 d][64 s] swizzled

    int tid = threadIdx.x;
    int w = tid >> 6, lane = tid & 63;
    int quad = lane >> 4, cc = lane & 15;
    int c7 = cc & 7;
    int bh = blockIdx.x, b = bh >> 3, h = bh & 7;
    int t0 = blockIdx.y * 64 + w * 16;                 // wave-owned t chunk (16 rows)
    size_t kbase = (size_t)bh * 2048 * 64;
    size_t vbase = (size_t)b * 512 * 2048 + (size_t)h * 64 * 2048;

    // Q fragments (B-operand: col=cc -> t, k = kc*32+quad*8+j)
    short8 qf[2];
#pragma unroll
    for (int kc = 0; kc < 2; ++kc)
        qf[kc] = *(const short8*)(Q + kbase + (size_t)(t0 + cc) * 64 + kc * 32 + quad * 8);

    // shared offset table: row = rb*16+cc (s for K, d for V), swizzled 16B granule
    int koff[4][2];
#pragma unroll
    for (int rb = 0; rb < 4; ++rb)
#pragma unroll
        for (int kc = 0; kc < 2; ++kc)
            koff[rb][kc] = (rb * 16 + cc) * 64 + (((kc * 4 + quad) ^ c7) * 8);

    // DMA staging: pre-swizzled global source, linear LDS dest (wave-uniform base + lane*16B)
    int sA = tid >> 3, cA = tid & 7;
    int csw = (cA ^ (sA & 7)) * 8;
    const short* gK = Kg + kbase + (size_t)sA * 64 + csw;
    const short* gV = Vt + vbase + (size_t)sA * 2048 + csw;
    int ldd = tid * 8;

    auto stage = [&](int cur, int it) {
        short* Kn = KbufL + cur * 4096;
        short* Vn = VbufL + cur * 4096;
        gload_lds16(gK + it * 4096,               Kn + ldd);           // K rows it*64 + [0,32)
        gload_lds16(gK + it * 4096 + 2048,        Kn + ldd + 2048);    // K rows it*64 + [32,64)
        gload_lds16(gV + it * 64,                 Vn + ldd);           // V^T rows [0,32), cols it*64
        gload_lds16(gV + it * 64 + 32 * 2048,     Vn + ldd + 2048);    // V^T rows [32,64)
    };

    stage(0, 0);

    float4_ o[4] = {};            // o[db]: O[t16][d = db*16+cc]
    float lp = 0.f;               // partial row-sum for t=cc over this lane's s-slots

#pragma unroll 2
    for (int it = 0; it < 32; ++it) {
        int cur = it & 1;
        __syncthreads();                        // buf[cur] staged (vmcnt drained pre-barrier); buf[cur^1] free
        if (it < 31) stage(cur ^ 1, it + 1);    // DMA next tile, lands during compute
        const short* Kt  = KbufL + cur * 4096;
        const short* Vtt = VbufL + cur * 4096;

        // ---- QK^T: acc[sb] = D[s16][t16], lane: col=cc->t, row=quad*4+r->s ----
        float4_ acc[4];
        __builtin_amdgcn_s_setprio(1);
#pragma unroll
        for (int sb = 0; sb < 4; ++sb) {
            short8 kf0 = *(const short8*)(Kt + koff[sb][0]);
            short8 kf1 = *(const short8*)(Kt + koff[sb][1]);
            float4_ z = {0.f, 0.f, 0.f, 0.f};
            z = __builtin_amdgcn_mfma_f32_16x16x32_bf16(kf0, qf[0], z, 0, 0, 0);
            acc[sb] = __builtin_amdgcn_mfma_f32_16x16x32_bf16(kf1, qf[1], z, 0, 0, 0);
        }
        __builtin_amdgcn_s_setprio(0);

        // ---- exp2 + wave-local row-sum + pack to bf16x2 words ----
        unsigned Wp[4][2];                      // [sb][word]: word w = P[s=sb*16+quad*4+2w+{0,1}][t=cc]
#pragma unroll
        for (int sb = 0; sb < 4; ++sb) {
            float x0 = __builtin_amdgcn_exp2f(acc[sb][0]);
            float x1 = __builtin_amdgcn_exp2f(acc[sb][1]);
            float x2 = __builtin_amdgcn_exp2f(acc[sb][2]);
            float x3 = __builtin_amdgcn_exp2f(acc[sb][3]);
            lp += (x0 + x1) + (x2 + x3);
            Wp[sb][0] = pk2bf(x0, x1);
            Wp[sb][1] = pk2bf(x2, x3);
        }

        // ---- in-register transpose P -> PV A-fragments (validated permlane butterfly) ----
        short8 pa[2];
#pragma unroll
        for (int kc = 0; kc < 2; ++kc) {
            unsigned a0 = Wp[2 * kc][0], a1 = Wp[2 * kc][1];
            unsigned b0 = Wp[2 * kc + 1][0], b1 = Wp[2 * kc + 1][1];
            pl32swap(a0, b0); pl32swap(a1, b1);
            pl16swap(a0, b0); pl16swap(a1, b1);
            U4 u; u.u[0] = a0; u.u[1] = a1; u.u[2] = b0; u.u[3] = b1;
            pa[kc] = u.s;
        }

        // ---- PV: o[db] += P^T[t16][s32] x V[s32][d16] (V frags broadcast from LDS) ----
        __builtin_amdgcn_s_setprio(1);
#pragma unroll
        for (int db = 0; db < 4; ++db) {
            short8 vf0 = *(const short8*)(Vtt + koff[db][0]);
            short8 vf1 = *(const short8*)(Vtt + koff[db][1]);
            o[db] = __builtin_amdgcn_mfma_f32_16x16x32_bf16(pa[0], vf0, o[db], 0, 0, 0);
            o[db] = __builtin_amdgcn_mfma_f32_16x16x32_bf16(pa[1], vf1, o[db], 0, 0, 0);
        }
        __builtin_amdgcn_s_setprio(0);
    }

    // ---- epilogue: wave-local softmax denominators, scale, store ----
    float s = lp;
    s += __shfl_xor(s, 16, 64);
    s += __shfl_xor(s, 32, 64);                 // lane holds full denom for t = cc
    float inv = 1.0f / s;
#pragma unroll
    for (int r = 0; r < 4; ++r) {
        int tl = quad * 4 + r;
        float iv = __shfl(inv, tl, 64);         // pull denom for this o-row (lane tl has cc=tl)
        size_t rowbase = ((size_t)(b * 2048 + t0 + tl)) * 512 + h * 64;
#pragma unroll
        for (int db = 0; db < 4; ++db)
            AO[rowbase + db * 16 + cc] = f2bf(o[db][r] * iv);
    }
}

// ---------------- output GEMM v2: 128x64 tiles, BK=64, VGPR-pipelined (qkv-clone), C fp32 ----------------
// grid (8, 64) = 512 blocks (2/CU). Wave (wr,wc): rows wr*64+[0,64), cols wc*32+[0,32).
__global__ __launch_bounds__(256) void gemm_out(const short* __restrict__ A, const short* __restrict__ B,
                                                float* __restrict__ C) {
    __shared__ __align__(16) short smemAB[8192 + 4096];   // At 16 KB | Bt 8 KB
    short* At = smemAB;
    short* Bt = smemAB + 8192;
    constexpr int K = 512;
    int tid = threadIdx.x;
    int wid = tid >> 6, lane = tid & 63;
    int quad = lane >> 4, cc = lane & 15;
    int c7 = cc & 7;
    int wr = wid >> 1, wc = wid & 1;
    int m0 = blockIdx.y * 128, n0 = blockIdx.x * 64;

    // staging: A 4 chunks, B 2 chunks (16B each) per thread, XOR-swizzled k-offsets
    const short* gA[4]; const short* gB[2]; int lofsA[4], lofsB[2];
#pragma unroll
    for (int p = 0; p < 4; ++p) {
        int slot = p * 256 + tid;          // 0..1023 -> A rows 0..127
        int r = slot >> 3, c = slot & 7;
        int cs = (c ^ (r & 7)) * 8;
        gA[p] = A + (size_t)(m0 + r) * K + cs;
        lofsA[p] = slot * 8;
    }
#pragma unroll
    for (int p = 0; p < 2; ++p) {
        int slot = p * 256 + tid;          // 0..511 -> B rows 0..63
        int r = slot >> 3, c = slot & 7;
        int cs = (c ^ (r & 7)) * 8;
        gB[p] = B + (size_t)(n0 + r) * K + cs;
        lofsB[p] = slot * 8;
    }
    short8 arg[4], brg[2];
#pragma unroll
    for (int p = 0; p < 4; ++p) arg[p] = *(const short8*)gA[p];
#pragma unroll
    for (int p = 0; p < 2; ++p) brg[p] = *(const short8*)gB[p];

    float4_ acc[4][2] = {};

    for (int kk = 0; kk < K; kk += 64) {
        __syncthreads();                    // prev iter's LDS reads done
#pragma unroll
        for (int p = 0; p < 4; ++p) *(short8*)(At + lofsA[p]) = arg[p];
#pragma unroll
        for (int p = 0; p < 2; ++p) *(short8*)(Bt + lofsB[p]) = brg[p];
        if (kk < K - 64) {
#pragma unroll
            for (int p = 0; p < 4; ++p) arg[p] = *(const short8*)(gA[p] + kk + 64);
#pragma unroll
            for (int p = 0; p < 2; ++p) brg[p] = *(const short8*)(gB[p] + kk + 64);
        }
        __syncthreads();                    // tile visible
#pragma unroll
        for (int kc = 0; kc < 2; ++kc) {
            short8 af[4], bf[2];
#pragma unroll
            for (int i = 0; i < 4; ++i)
                af[i] = *(const short8*)(At + (wr * 64 + i * 16 + cc) * 64 + (((kc * 4 + quad) ^ c7) * 8));
#pragma unroll
            for (int j = 0; j < 2; ++j)
                bf[j] = *(const short8*)(Bt + (wc * 32 + j * 16 + cc) * 64 + (((kc * 4 + quad) ^ c7) * 8));
#pragma unroll
            for (int i = 0; i < 4; ++i)
#pragma unroll
                for (int j = 0; j < 2; ++j)
                    acc[i][j] = __builtin_amdgcn_mfma_f32_16x16x32_bf16(af[i], bf[j], acc[i][j], 0, 0, 0);
        }
    }

#pragma unroll
    for (int i = 0; i < 4; ++i)
#pragma unroll
        for (int j = 0; j < 2; ++j)
#pragma unroll
            for (int r = 0; r < 4; ++r) {
                int gm = m0 + wr * 64 + i * 16 + quad * 4 + r;
                int gn = n0 + wc * 32 + j * 16 + cc;
                C[(size_t)gm * 512 + gn] = acc[i][j][r];
            }
}

extern "C" void kernel_launch(void* const* d_in, const int* in_sizes, int n_in,
                              void* d_out, int out_size, void* d_ws, size_t ws_size,
                              hipStream_t stream) {
    const float* X  = (const float*)d_in[0];
    const int* mask = (const int*)d_in[1];
    const float* Wq = (const float*)d_in[2];
    const float* Wk = (const float*)d_in[3];
    const float* Wv = (const float*)d_in[4];
    const float* Wo = (const float*)d_in[5];

    char* ws = (char*)d_ws;
    short* Xbf   = (short*)(ws + 0);              // 8192*512*2       = 8,388,608
    short* Wqkvb = (short*)(ws + 8388608);        // 1536*512*2       = 1,572,864
    short* Wob   = (short*)(ws + 9961472);        // 512*512*2        =   524,288
    short* Qb    = (short*)(ws + 10485760);       // [b,h,n,dh] bf16  = 8,388,608
    short* Kb    = (short*)(ws + 18874368);       // [b,h,n,dh] bf16  = 8,388,608
    short* Vtb   = (short*)(ws + 27262976);       // [b,dv,n]  bf16   = 8,388,608
    short* AOb   = (short*)(ws + 35651584);       // [b,n,512] bf16   = 8,388,608

    cvt_kernel<<<5120, 256, 0, stream>>>(X, Wq, Wk, Wv, Wo, Xbf, Wqkvb, Wob);
    gemm_qkv<<<dim3(12, 64), 256, 0, stream>>>(Xbf, Wqkvb, mask, Qb, Kb, Vtb);
    attn_kernel<<<dim3(32, 32), 256, 0, stream>>>(Qb, Kb, Vtb, AOb);
    gemm_out<<<dim3(8, 64), 256, 0, stream>>>(AOb, Wob, (float*)d_out);
}